// Round 11
// baseline (307.902 us; speedup 1.0000x reference)
//
#include <hip/hip_runtime.h>

#define NN 100000
#define NE 1600000
#define DIM 64
#define NR 391      // regions = ceil(NN/256), key = dst>>8
#define BP 400      // partition blocks, 4000 edges each
#define MH (NR * BP)  // 156400 histogram cells, r-major
#define NSB2 611    // ceil(MH/256)
#define IDXCAP 1536 // LDS-staged csr2 slice cap per 64-node tile (mean 1024, 16 sigma)

typedef unsigned short u16;
typedef unsigned int u32;

__device__ __forceinline__ u16 f2b(float f) {  // f32 -> bf16 RNE
  union { float f; u32 u; } c; c.f = f;
  u32 u = c.u;
  u += 0x7FFF + ((u >> 16) & 1);
  return (u16)(u >> 16);
}
__device__ __forceinline__ float b2f(u16 h) {
  union { u32 u; float f; } c; c.u = ((u32)h) << 16;
  return c.f;
}
__device__ __forceinline__ float blo(u32 v) {
  union { u32 u; float f; } c; c.u = v << 16;
  return c.f;
}
__device__ __forceinline__ float bhi(u32 v) {
  union { u32 u; float f; } c; c.u = v & 0xFFFF0000u;
  return c.f;
}
__device__ __forceinline__ u32 pk(float lo, float hi) {  // pack 2 bf16
  return ((u32)f2b(hi) << 16) | (u32)f2b(lo);
}

// x (f32) -> xh (bf16), 4 elems/thread, exact grid
__global__ __launch_bounds__(256) void k_tobf(const float* __restrict__ x,
                                              u16* __restrict__ xh) {
  int i = blockIdx.x * 256 + threadIdx.x;
  float4 v = ((const float4*)x)[i];
  ushort4 o;
  o.x = f2b(v.x); o.y = f2b(v.y); o.z = f2b(v.z); o.w = f2b(v.w);
  ((ushort4*)xh)[i] = o;
}

// ---- deterministic two-pass region partition (no global data atomics) ----

// pass 1: per-block region histogram in LDS -> H[r][b]
__global__ __launch_bounds__(256) void k_phist(const int* __restrict__ ei,
                                               int* __restrict__ Hmat) {
  __shared__ int lh[NR];
  const int t = threadIdx.x;
  const int b = blockIdx.x;
  for (int i = t; i < NR; i += 256) lh[i] = 0;
  __syncthreads();
  const int e0 = b * 4000;
  for (int k = 0; k < 16; ++k) {
    int o = k * 256 + t;
    if (o < 4000) atomicAdd(&lh[ei[NE + e0 + o] >> 8], 1);
  }
  __syncthreads();
  for (int i = t; i < NR; i += 256) Hmat[i * BP + b] = lh[i];
}

// flat exclusive scan of Hmat[MH]: per-block scan -> block sums
__global__ __launch_bounds__(256) void k_sA(int* __restrict__ a,
                                            int* __restrict__ bsum) {
  __shared__ int buf[256];
  const int t = threadIdx.x;
  const int i = blockIdx.x * 256 + t;
  int v = (i < MH) ? a[i] : 0;
  buf[t] = v;
  __syncthreads();
  for (int off = 1; off < 256; off <<= 1) {
    int u = (t >= off) ? buf[t - off] : 0;
    __syncthreads();
    buf[t] += u;
    __syncthreads();
  }
  if (i < MH) a[i] = buf[t] - v;
  if (t == 255) bsum[blockIdx.x] = buf[255];
}

// scan the 611 block sums in place (exclusive)
__global__ __launch_bounds__(1024) void k_sB(int* __restrict__ bsum) {
  __shared__ int buf[1024];
  const int t = threadIdx.x;
  int v = (t < NSB2) ? bsum[t] : 0;
  buf[t] = v;
  __syncthreads();
  for (int off = 1; off < 1024; off <<= 1) {
    int u = (t >= off) ? buf[t - off] : 0;
    __syncthreads();
    buf[t] += u;
    __syncthreads();
  }
  if (t < NSB2) bsum[t] = buf[t] - v;
}

__global__ __launch_bounds__(256) void k_sC(int* __restrict__ a,
                                            const int* __restrict__ bsum) {
  int i = blockIdx.x * 256 + threadIdx.x;
  if (i < MH) a[i] += bsum[blockIdx.x];
}

// extract region starts from scanned H; set sentinels
__global__ __launch_bounds__(512) void k_rex(const int* __restrict__ Hs,
                                             int* __restrict__ rstart,
                                             int* __restrict__ nstartP) {
  int t = threadIdx.x;
  if (t < NR) rstart[t] = Hs[t * BP];
  if (t == 0) { rstart[NR] = NE; nstartP[NN] = NE; }
}

// pass 2: scatter with LDS cursors; (block,region) groups write consecutively
__global__ __launch_bounds__(256) void k_pfill(const int* __restrict__ ei,
                                               const int* __restrict__ Hs,
                                               int* __restrict__ bb) {
  __shared__ int lcur[NR];
  const int t = threadIdx.x;
  const int b = blockIdx.x;
  for (int i = t; i < NR; i += 256) lcur[i] = Hs[i * BP + b];
  __syncthreads();
  const int e0 = b * 4000;
  for (int k = 0; k < 16; ++k) {
    int o = k * 256 + t;
    if (o < 4000) {
      int e = e0 + o;
      int src = ei[e];
      int dst = ei[NE + e];
      int p = atomicAdd(&lcur[dst >> 8], 1);  // LDS atomic only
      bb[p] = src | ((dst & 255) << 17);      // src < 2^17
    }
  }
}

// one block per region: counting-sort region entries by node -> csr2 + nstartP
__global__ __launch_bounds__(256) void k_rsort(const int* __restrict__ rstart,
                                               const int* __restrict__ bb,
                                               int* __restrict__ csr2,
                                               int* __restrict__ nstartP) {
  __shared__ int nhist[256], ncur[256], buf[256];
  const int t = threadIdx.x;
  const int r = blockIdx.x;
  const int s = rstart[r];
  const int cnt = rstart[r + 1] - s;
  const int nb = r << 8;
  nhist[t] = 0;
  __syncthreads();
  for (int p = t; p < cnt; p += 256) atomicAdd(&nhist[bb[s + p] >> 17], 1);
  __syncthreads();
  int v = nhist[t];
  buf[t] = v;
  __syncthreads();
  for (int off = 1; off < 256; off <<= 1) {
    int u = (t >= off) ? buf[t - off] : 0;
    __syncthreads();
    buf[t] += u;
    __syncthreads();
  }
  int st = s + buf[t] - v;  // absolute start of node nb+t
  ncur[t] = st;
  if (nb + t < NN) nstartP[nb + t] = st;
  __syncthreads();
  for (int p = t; p < cnt; p += 256) {
    int e2 = bb[s + p];
    int pos = atomicAdd(&ncur[e2 >> 17], 1);
    csr2[pos] = e2 & 0x1FFFF;
  }
}

// ---- fused layer: staged sorted-CSR gather (row-paired, 16 loads in flight)
//      -> bf16-packed LDS tile -> 2-layer MLP (f32 acc) -> bf16 out ----
// 512 threads = 8 waves per 64-node tile: 4 blocks/CU == 32-wave cap, so every
// CU runs fully packed (grid 1563 >= 4*256). Wave owns 8 output cols (jcs
// wave-uniform -> scalar W loads). FINAL=1: fuse out = h2 @ Wf + bf (f32).
template <int FINAL>
__global__ __launch_bounds__(512, 8) void k_gin(const u16* __restrict__ xh,
                                                const int* __restrict__ nstartP,
                                                const int* __restrict__ csr2,
                                                const float* __restrict__ eps, int l,
                                                const float* __restrict__ W1,
                                                const float* __restrict__ b1,
                                                const float* __restrict__ W2,
                                                const float* __restrict__ b2,
                                                u16* __restrict__ outh,
                                                const float* __restrict__ Wf,
                                                const float* __restrict__ bf,
                                                float* __restrict__ outf) {
  __shared__ u32 tile32[64 * 33];  // bf16 pair per cell; stride 33 -> 2-way banks
  __shared__ int sidx[IDXCAP];
  __shared__ int sstart[65];
  const int tid = threadIdx.x;
  const int lane = tid & 63;
  const int wv = tid >> 6;   // 0..7
  const int h = lane >> 5;
  const int fl = lane & 31;
  const int base = blockIdx.x * 64;
  const int rows = min(64, NN - base);
  const float sc = 1.0f + eps[l];
  const float sch = (h == 0) ? sc : 0.0f;
  const u32* xu = (const u32*)xh;

  const int s0 = nstartP[base];
  const int cnt = nstartP[base + rows] - s0;
  if (tid <= rows) sstart[tid] = nstartP[base + tid];
  const int cs = min(cnt, IDXCAP);
  for (int p = tid; p < cs; p += 512) sidx[p] = csr2[s0 + p];
  __syncthreads();

  if (cnt <= IDXCAP) {
    for (int n = wv; n < rows; n += 16) {
      const int nB = n + 8;
      const bool hasB = nB < rows;
      const int stA = sstart[n];
      const int dA = sstart[n + 1] - stA;
      const int offA = (stA - s0) + h;
      const int mA = (dA + 1 - h) >> 1;
      int offB = 0, mB = 0;
      if (hasB) {
        int stB = sstart[nB];
        int dB = sstart[nB + 1] - stB;
        offB = (stB - s0) + h;
        mB = (dB + 1 - h) >> 1;
      }
      float A0[8], A1[8], B0[8], B1[8];
#pragma unroll
      for (int u = 0; u < 8; ++u) { A0[u] = 0.f; A1[u] = 0.f; B0[u] = 0.f; B1[u] = 0.f; }
      u32 usA = xu[(size_t)(base + n) * 32 + fl];
      A0[0] = sch * blo(usA); A1[0] = sch * bhi(usA);
      if (hasB) {
        u32 usB = xu[(size_t)(base + nB) * 32 + fl];
        B0[0] = sch * blo(usB); B1[0] = sch * bhi(usB);
      }
      float yA0 = 0.f, yA1 = 0.f, yB0 = 0.f, yB1 = 0.f;
      int i = 0;
      const int mMin = hasB ? min(mA, mB) : 0;
      for (; i + 8 <= mMin; i += 8) {  // joint: 16 row-loads in flight
        int ia[8], ib[8];
#pragma unroll
        for (int u = 0; u < 8; ++u) {
          ia[u] = sidx[offA + 2 * (i + u)];
          ib[u] = sidx[offB + 2 * (i + u)];
        }
        u32 va[8], vb[8];
#pragma unroll
        for (int u = 0; u < 8; ++u) {
          va[u] = xu[(size_t)ia[u] * 32 + fl];
          vb[u] = xu[(size_t)ib[u] * 32 + fl];
        }
#pragma unroll
        for (int u = 0; u < 8; ++u) {
          A0[u] += blo(va[u]); A1[u] += bhi(va[u]);
          B0[u] += blo(vb[u]); B1[u] += bhi(vb[u]);
        }
      }
      int iA = i;
      for (; iA + 4 <= mA; iA += 4) {
        int ia[4];
#pragma unroll
        for (int u = 0; u < 4; ++u) ia[u] = sidx[offA + 2 * (iA + u)];
        u32 va[4];
#pragma unroll
        for (int u = 0; u < 4; ++u) va[u] = xu[(size_t)ia[u] * 32 + fl];
#pragma unroll
        for (int u = 0; u < 4; ++u) { A0[u] += blo(va[u]); A1[u] += bhi(va[u]); }
      }
      for (; iA < mA; ++iA) {
        u32 u_ = xu[(size_t)sidx[offA + 2 * iA] * 32 + fl];
        yA0 += blo(u_); yA1 += bhi(u_);
      }
      int iB = i;
      for (; iB + 4 <= mB; iB += 4) {
        int ib[4];
#pragma unroll
        for (int u = 0; u < 4; ++u) ib[u] = sidx[offB + 2 * (iB + u)];
        u32 vb[4];
#pragma unroll
        for (int u = 0; u < 4; ++u) vb[u] = xu[(size_t)ib[u] * 32 + fl];
#pragma unroll
        for (int u = 0; u < 4; ++u) { B0[u] += blo(vb[u]); B1[u] += bhi(vb[u]); }
      }
      for (; iB < mB; ++iB) {
        u32 u_ = xu[(size_t)sidx[offB + 2 * iB] * 32 + fl];
        yB0 += blo(u_); yB1 += bhi(u_);
      }
      float eA0 = (((A0[0] + A0[1]) + (A0[2] + A0[3])) + ((A0[4] + A0[5]) + (A0[6] + A0[7]))) + yA0;
      float eA1 = (((A1[0] + A1[1]) + (A1[2] + A1[3])) + ((A1[4] + A1[5]) + (A1[6] + A1[7]))) + yA1;
      eA0 += __shfl_xor(eA0, 32, 64);
      eA1 += __shfl_xor(eA1, 32, 64);
      if (h == 0) tile32[n * 33 + fl] = pk(eA0, eA1);
      if (hasB) {
        float eB0 = (((B0[0] + B0[1]) + (B0[2] + B0[3])) + ((B0[4] + B0[5]) + (B0[6] + B0[7]))) + yB0;
        float eB1 = (((B1[0] + B1[1]) + (B1[2] + B1[3])) + ((B1[4] + B1[5]) + (B1[6] + B1[7]))) + yB1;
        eB0 += __shfl_xor(eB0, 32, 64);
        eB1 += __shfl_xor(eB1, 32, 64);
        if (h == 0) tile32[nB * 33 + fl] = pk(eB0, eB1);
      }
    }
  } else {
    // fallback (statistically never): indices straight from global csr2
    for (int n = wv; n < rows; n += 8) {
      const int st = sstart[n];
      const int d = sstart[n + 1] - st;
      const int m = (d + 1 - h) >> 1;
      u32 us = xu[(size_t)(base + n) * 32 + fl];
      float e0 = sch * blo(us), e1 = sch * bhi(us);
      for (int i2 = 0; i2 < m; ++i2) {
        u32 u_ = xu[(size_t)csr2[st + h + 2 * i2] * 32 + fl];
        e0 += blo(u_); e1 += bhi(u_);
      }
      e0 += __shfl_xor(e0, 32, 64);
      e1 += __shfl_xor(e1, 32, 64);
      if (h == 0) tile32[n * 33 + fl] = pk(e0, e1);
    }
  }
  __syncthreads();

  // MLP. lane = node row; wave owns cols [jcs, jcs+8), jcs in SGPR.
  const int jcs = __builtin_amdgcn_readfirstlane(wv * 8);
  const int jh = jcs >> 1;  // packed-pair col base (4 pairs)
  float acc[8];
#pragma unroll
  for (int j = 0; j < 8; ++j) acc[j] = b1[jcs + j];
#pragma unroll 4
  for (int kk = 0; kk < 32; ++kk) {
    u32 pr = tile32[lane * 33 + kk];
    float a0 = blo(pr), a1 = bhi(pr);
#pragma unroll
    for (int j = 0; j < 8; ++j)
      acc[j] = fmaf(a1, W1[(2 * kk + 1) * 64 + jcs + j],
                    fmaf(a0, W1[(2 * kk) * 64 + jcs + j], acc[j]));
  }
  __syncthreads();
#pragma unroll
  for (int j2 = 0; j2 < 4; ++j2)
    tile32[lane * 33 + jh + j2] =
        pk(fmaxf(acc[2 * j2], 0.0f), fmaxf(acc[2 * j2 + 1], 0.0f));
  __syncthreads();

#pragma unroll
  for (int j = 0; j < 8; ++j) acc[j] = b2[jcs + j];
#pragma unroll 4
  for (int kk = 0; kk < 32; ++kk) {
    u32 pr = tile32[lane * 33 + kk];
    float a0 = blo(pr), a1 = bhi(pr);
#pragma unroll
    for (int j = 0; j < 8; ++j)
      acc[j] = fmaf(a1, W2[(2 * kk + 1) * 64 + jcs + j],
                    fmaf(a0, W2[(2 * kk) * 64 + jcs + j], acc[j]));
  }
  __syncthreads();
#pragma unroll
  for (int j2 = 0; j2 < 4; ++j2)
    tile32[lane * 33 + jh + j2] =
        pk(fmaxf(acc[2 * j2], 0.0f), fmaxf(acc[2 * j2 + 1], 0.0f));
  __syncthreads();

  if constexpr (FINAL == 0) {
    // coalesced packed bf16 store: 16 row-streams across 8 waves
    u32* o32 = (u32*)outh;
    for (int n2 = wv * 2 + h; n2 < rows; n2 += 16)
      o32[(size_t)(base + n2) * 32 + fl] = tile32[n2 * 33 + fl];
  } else {
    // GEMM3: out(f32) = h2 @ Wf + bf (no relu), h2 packed in tile32
#pragma unroll
    for (int j = 0; j < 8; ++j) acc[j] = bf[jcs + j];
#pragma unroll 4
    for (int kk = 0; kk < 32; ++kk) {
      u32 pr = tile32[lane * 33 + kk];
      float a0 = blo(pr), a1 = bhi(pr);
#pragma unroll
      for (int j = 0; j < 8; ++j)
        acc[j] = fmaf(a1, Wf[(2 * kk + 1) * 64 + jcs + j],
                      fmaf(a0, Wf[(2 * kk) * 64 + jcs + j], acc[j]));
    }
    if (lane < rows) {
      float4* op = (float4*)(outf + (size_t)(base + lane) * 64 + jcs);
      op[0] = make_float4(acc[0], acc[1], acc[2], acc[3]);
      op[1] = make_float4(acc[4], acc[5], acc[6], acc[7]);
    }
  }
}

extern "C" void kernel_launch(void* const* d_in, const int* in_sizes, int n_in,
                              void* d_out, int out_size, void* d_ws, size_t ws_size,
                              hipStream_t stream) {
  const float* x   = (const float*)d_in[0];
  const int*   ei  = (const int*)d_in[1];
  const float* W1  = (const float*)d_in[2];
  const float* b1  = (const float*)d_in[3];
  const float* W2  = (const float*)d_in[4];
  const float* b2  = (const float*)d_in[5];
  const float* eps = (const float*)d_in[6];
  const float* Wf  = (const float*)d_in[7];
  const float* bf  = (const float*)d_in[8];

  // ws: xh0 | xh1 [NN*64 u16 each, 12.8MB] | csr2[NE, 6.4MB] | nstartP[NN+1]
  //     | Hmat[MH, 626KB] | bsum[NSB2] | rstart[NR+1]   (~33.1 MB)
  u16* xh0 = (u16*)d_ws;
  u16* xh1 = xh0 + (size_t)NN * DIM;
  int* csr2    = (int*)(xh1 + (size_t)NN * DIM);
  int* nstartP = csr2 + NE;
  int* Hmat    = nstartP + NN + 1;
  int* bsum    = Hmat + MH;
  int* rstart  = bsum + NSB2;
  // bb lives in d_out (dead until layer-2 k_gin writes the real output)
  int* bb = (int*)d_out;

  const int grid_conv = NN * DIM / 4 / 256;  // 6250, exact
  const int grid_mlp  = (NN + 63) / 64;      // 1563

  k_tobf<<<grid_conv, 256, 0, stream>>>(x, xh0);
  k_phist<<<BP, 256, 0, stream>>>(ei, Hmat);
  k_sA<<<NSB2, 256, 0, stream>>>(Hmat, bsum);
  k_sB<<<1, 1024, 0, stream>>>(bsum);
  k_sC<<<NSB2, 256, 0, stream>>>(Hmat, bsum);
  k_rex<<<1, 512, 0, stream>>>(Hmat, rstart, nstartP);
  k_pfill<<<BP, 256, 0, stream>>>(ei, Hmat, bb);
  k_rsort<<<NR, 256, 0, stream>>>(rstart, bb, csr2, nstartP);

  // bf16 ping-pong: L0 xh0->xh1, L1 xh1->xh0, L2 xh0 -> (fused final) d_out f32
  k_gin<0><<<grid_mlp, 512, 0, stream>>>(xh0, nstartP, csr2, eps, 0,
                                         W1, b1, W2, b2, xh1, Wf, bf, nullptr);
  k_gin<0><<<grid_mlp, 512, 0, stream>>>(xh1, nstartP, csr2, eps, 1,
                                         W1 + 64 * 64, b1 + 64, W2 + 64 * 64, b2 + 64,
                                         xh0, Wf, bf, nullptr);
  k_gin<1><<<grid_mlp, 512, 0, stream>>>(xh0, nstartP, csr2, eps, 2,
                                         W1 + 2 * 64 * 64, b1 + 2 * 64,
                                         W2 + 2 * 64 * 64, b2 + 2 * 64,
                                         xh1, Wf, bf, (float*)d_out);
}